// Round 13
// baseline (221.131 us; speedup 1.0000x reference)
//
#include <hip/hip_runtime.h>

#define NLOC  10
#define NGI   13
#define NPAIR 55
#define EPB   16           // elements per chunk = per wave
#define TPB   64           // 1 wave per block: NO barriers anywhere in the loop

// per-buffer float offsets (regions packed in DMA granule order)
#define B_DW   4160        // EPB*260 nx floats
#define B_R0   4368        // +EPB*13
#define B_CI   4528
#define B_CN   4688
#define BUF_FL 4848        // 19392 B per buffer
#define W_N    (2 * BUF_FL)
#define W_TOT  (W_N + 130) // 9826 fl = 39304 B -> 4 blocks/CU = 4 indep pipelines

// granule (16B) region END boundaries (per wave-chunk)
#define GE_NX  1040
#define GE_DW  1092
#define GE_R0  1132
#define GE_CI  1172
#define GE_CN  1212        // 19 stage instrs (19*64 = 1216)

// output staging (reuses the consumed buffer): [bd 1600][dg 160][r0 160] floats
#define OS_DG   1600
#define OS_R0   1760
#define OS_GRAN 480        // granules -> 8 coalesced dwordx4 store instrs

typedef float vf2 __attribute__((ext_vector_type(2)));
typedef float vf4 __attribute__((ext_vector_type(4)));

__device__ __forceinline__ constexpr int pidx(int i, int j) {   // requires i<=j
    return i * NLOC - (i * (i - 1)) / 2 + (j - i);
}

// async global->LDS, 16B/lane; lds base wave-uniform, HW adds lane*16
__device__ __forceinline__ void stage16(const float* gsrc, float* lds) {
    __builtin_amdgcn_global_load_lds(
        (const __attribute__((address_space(1))) void*)gsrc,
        (__attribute__((address_space(3))) void*)lds, 16, 0, 0);
}

__global__ __launch_bounds__(TPB, 1) void fem_kernel(
    const float* __restrict__ r0g,
    const float* __restrict__ cig,
    const float* __restrict__ cng,
    const float* __restrict__ kp,
    const float* __restrict__ dtp,
    const float* __restrict__ nmat,
    const float* __restrict__ nx,
    const float* __restrict__ dwei,
    float* __restrict__ out,
    int nele)
{
    __shared__ float sm[W_TOT];

    const int t       = threadIdx.x;
    const int nchunks = (nele + EPB - 1) / EPB;
    const int gs      = gridDim.x;

    // stage one chunk's working set into buffer b: 19 DMA instrs, no VGPR roundtrip
    auto stage_chunk = [&](int b, int c) {
        const long ce0  = (long)c * EPB;
        const int  crem = min(EPB, nele - (int)ce0);
        const float* snx = nx   + (size_t)ce0 * 260;
        const float* sdw = dwei + (size_t)ce0 * 13;
        const float* sr0 = r0g  + (size_t)ce0 * 10;
        const float* sci = cig  + (size_t)ce0 * 10;
        const float* scn = cng  + (size_t)ce0 * 10;
        const int cnx = crem * 260, cdw = crem * 13, c10 = crem * 10;
        float* ldsb = sm + b * BUF_FL;       // wave-uniform base
        #pragma unroll
        for (int k = 0; k < 19; ++k) {
            const int G = k * TPB + t;       // granule; LDS float off = G*4
            const float* src; int rel, capf;
            if      (G < GE_NX) { src = snx; rel = G;         capf = cnx; }
            else if (G < GE_DW) { src = sdw; rel = G - GE_NX; capf = cdw; }
            else if (G < GE_R0) { src = sr0; rel = G - GE_DW; capf = c10; }
            else if (G < GE_CI) { src = sci; rel = G - GE_R0; capf = c10; }
            else if (G < GE_CN) { src = scn; rel = G - GE_CI; capf = c10; }
            else continue;
            if (rel * 4 < capf) stage16(src + (size_t)rel * 4, ldsb + k * TPB * 4);
        }
    };

    // per-element thread roles (chunk-invariant)
    const int  eloc = t >> 2;            // 0..15
    const int  d    = (t >> 1) & 1;      // spatial dim (stiffness)
    const int  h    = t & 1;             // g-parity (stiffness)
    const int  q    = t & 3;             // g-stride-4 slot (mass, epilogue)
    const float kk  = kp[0];
    const float idt = 1.0f / dtp[0];
    const float* smn = sm + W_N;

    // prologue: n table FIRST (its loads' implicit waits precede the pipeline),
    // then chunk 0 stage. Single wave: lockstep, no barrier ever needed.
    for (int w = t; w < 130; w += TPB) sm[W_N + w] = nmat[w];
    int c = blockIdx.x;
    if (c < nchunks) stage_chunk(0, c);

    int cur = 0;
    for (; c < nchunks; c += gs) {
        const int next = c + gs;
        // T3/T4: counted vmcnt, never 0 mid-loop. Composition at the wait:
        // [DMA_cur 19][stores_prev 8][DMA_next 19] -> vmcnt(19) drains cur+stores,
        // leaves next's DMA in flight under the whole compute phase.
        if (next < nchunks) {
            stage_chunk(cur ^ 1, next);
            asm volatile("s_waitcnt vmcnt(19)" ::: "memory");
        } else {
            asm volatile("s_waitcnt vmcnt(0)" ::: "memory");
        }

        // -------- compute chunk c from buf[cur]: zero global loads --------
        const long e0   = (long)c * EPB;
        const int  rem  = min(EPB, nele - (int)e0);
        const bool live = eloc < rem;

        const float* bb   = sm + cur * BUF_FL;
        const float* smnx = bb + eloc * 260 + d * 130;
        const float* smdw = bb + B_DW + eloc * 13;
        const float* smr0 = bb + B_R0 + eloc * 10;
        const float* smci = bb + B_CI + eloc * 10;
        const float* smcn = bb + B_CN + eloc * 10;

        float civ[NLOC], dif[NLOC];
        #pragma unroll
        for (int l = 0; l < NLOC; ++l) civ[l] = smci[l];
        #pragma unroll
        for (int l = 0; l < NLOC; ++l) dif[l] = smcn[l] - civ[l];

        float acc[NPAIR];
        #pragma unroll
        for (int p = 0; p < NPAIR; ++p) acc[p] = 0.0f;
        float r0a[NLOC];
        #pragma unroll
        for (int i = 0; i < NLOC; ++i) r0a[i] = 0.0f;

        // stiffness: dim d, g = 2*it + h (7 iters, last guarded)
        #pragma unroll
        for (int it = 0; it < 7; ++it) {
            const int   graw = 2 * it + h;
            const int   g    = graw < NGI ? graw : NGI - 1;
            const float wv   = graw < NGI ? kk * smdw[g] : 0.0f;
            float col[NLOC];
            #pragma unroll
            for (int l = 0; l < NLOC; ++l) col[l] = smnx[l * 13 + g];
            float u = 0.0f;
            #pragma unroll
            for (int l = 0; l < NLOC; ++l) u = fmaf(col[l], civ[l], u);
            const float uw = u * wv;
            #pragma unroll
            for (int i = 0; i < NLOC; ++i) {
                const float ti = col[i] * wv;
                #pragma unroll
                for (int j = i; j < NLOC; ++j)
                    acc[pidx(i, j)] = fmaf(ti, col[j], acc[pidx(i, j)]);
                r0a[i] = fmaf(-col[i], uw, r0a[i]);
            }
        }

        // mass: g = q + 4*it (4 iters, guarded); r0 += nn/dt*(cn-ci)
        #pragma unroll
        for (int it = 0; it < 4; ++it) {
            const int   graw = q + 4 * it;
            const int   g    = graw < NGI ? graw : NGI - 1;
            const float wv   = graw < NGI ? idt * smdw[g] : 0.0f;
            float ncol[NLOC];
            #pragma unroll
            for (int l = 0; l < NLOC; ++l) ncol[l] = smn[l * 13 + g];
            float wd = 0.0f;
            #pragma unroll
            for (int l = 0; l < NLOC; ++l) wd = fmaf(ncol[l], dif[l], wd);
            #pragma unroll
            for (int i = 0; i < NLOC; ++i) {
                const float ti = ncol[i] * wv;
                #pragma unroll
                for (int j = i; j < NLOC; ++j)
                    acc[pidx(i, j)] = fmaf(ti, ncol[j], acc[pidx(i, j)]);
                r0a[i] = fmaf(ti, wd, r0a[i]);
            }
        }

        // combine the 4 partial sums (quad butterfly)
        #pragma unroll
        for (int p = 0; p < NPAIR; ++p) {
            acc[p] += __shfl_xor(acc[p], 1);
            acc[p] += __shfl_xor(acc[p], 2);
        }
        #pragma unroll
        for (int i = 0; i < NLOC; ++i) {
            r0a[i] += __shfl_xor(r0a[i], 1);
            r0a[i] += __shfl_xor(r0a[i], 2);
        }

        // -------- epilogue: stage outputs in LDS (overwrites consumed buf[cur];
        // single-wave lockstep => all reads above already issued) --------
        float* smout = sm + cur * BUF_FL;
        if (live) {
            #pragma unroll
            for (int i = 0; i < NLOC; ++i) {
                if ((i & 3) == q) {
                    float row[NLOC];
                    #pragma unroll
                    for (int j = 0; j < NLOC; ++j) {
                        const int lo = i < j ? i : j, hi = i < j ? j : i;
                        row[j] = acc[pidx(lo, hi)];
                    }
                    #pragma unroll
                    for (int u2 = 0; u2 < 5; ++u2) {
                        vf2 v = { row[2*u2], row[2*u2+1] };
                        *reinterpret_cast<vf2*>(&smout[eloc * 100 + i * 10 + 2 * u2]) = v;
                    }
                    smout[OS_DG + eloc * 10 + i] = row[i];
                    smout[OS_R0 + eloc * 10 + i] = smr0[i] + r0a[i];
                }
            }
        }

        // flush: 8 wave-contiguous 1KB nontemporal stores (full-line, no RMW)
        const int remg = rem * 30;             // valid granules (rem*480/16)
        #pragma unroll
        for (int k = 0; k < 8; ++k) {
            const int G = k * TPB + t;
            if (G < remg && G < OS_GRAN) {
                vf4 v = *reinterpret_cast<const vf4*>(&smout[G * 4]);
                float* dst;
                if (G < 400)
                    dst = out + (size_t)e0 * 100 + (size_t)G * 4;
                else if (G < 440)
                    dst = out + (size_t)nele * 100 + (size_t)e0 * 10 + (size_t)(G - 400) * 4;
                else
                    dst = out + (size_t)nele * 110 + (size_t)e0 * 10 + (size_t)(G - 440) * 4;
                __builtin_nontemporal_store(v, reinterpret_cast<vf4*>(dst));
            }
        }

        cur ^= 1;
    }
}

extern "C" void kernel_launch(void* const* d_in, const int* in_sizes, int n_in,
                              void* d_out, int out_size, void* d_ws, size_t ws_size,
                              hipStream_t stream) {
    const float* r0   = (const float*)d_in[0];
    const float* ci   = (const float*)d_in[1];
    const float* cn   = (const float*)d_in[2];
    const float* k    = (const float*)d_in[3];
    const float* dt   = (const float*)d_in[4];
    const float* nmat = (const float*)d_in[5];
    const float* nx   = (const float*)d_in[6];
    const float* dw   = (const float*)d_in[7];
    const int nele = in_sizes[7] / NGI;

    const int nchunks = (nele + EPB - 1) / EPB;
    const int nb = min(1024, nchunks);       // 4 pipelines/CU, grid-stride
    fem_kernel<<<nb, TPB, 0, stream>>>(r0, ci, cn, k, dt, nmat, nx, dw,
                                       (float*)d_out, nele);
}